// Round 6
// baseline (76.578 us; speedup 1.0000x reference)
//
#include <hip/hip_runtime.h>

// FractalEmbedding: out[b,l,d] = scale * sum_f feats(token)[f] * W[d,f]
// feats = 8-step Julia iteration on c_table[token], interleaved (zr,zi).
//
// B=8, L=8192 -> 65536 tokens; D=1024; 16 features. Output 268 MB f32.
// R5 = 50.3us ~= 38us store-floor + ~12us unhidden VALU/LDS. Issue count is
// no longer the lever; OVERLAP is. This version software-pipelines:
//  - two-phase ping-pong body (4 tokens/iter): phase A prefetches next
//    pair's feats into reg-set B while computing+storing the current pair
//    from reg-set A; phase B swaps. No rotation movs; lgkm waits are
//    covered by 128 cy of FMAs; store source regs alternate between two
//    sets so 2-4 stores stay in flight (vmcnt(2+) instead of per-iter 0).
//  - unchanged from R5: LDS feats dedup (bit-identical Julia, computed once
//    per block by threads 0..63), packed floatx2 dot (v_pk_fma_f32, per-dim
//    chain order = reference k ascending), plain float4 stores, zero global
//    loads in main loop, GRID=1024/BLOCK=256/TPB=64 exact residency.

#define STEPS 8
#define NFEAT (2 * STEPS)
#define EMBED 1024
#define NTOK (8 * 8192)
#define TPB 64                 // tokens per block
#define BLOCK 256
#define GRID (NTOK / TPB)      // 1024

typedef float floatx2 __attribute__((ext_vector_type(2)));

__global__ __launch_bounds__(BLOCK, 4) void FractalEmbedding_30365418782757_kernel(
    const int* __restrict__ tok,
    const float* __restrict__ ctab,   // (V, 2)
    const float* __restrict__ W,      // (1024, 16) row-major
    const float* __restrict__ scale_p,
    float* __restrict__ out)          // (NTOK, 1024)
{
    const int t = threadIdx.x;  // thread t -> output dims 4t .. 4t+3
    const float s = *scale_p;

    __shared__ float4 fs4[TPB * 4];   // 4 KB: per-token features, 4x float4 each

    const int base = blockIdx.x * TPB;

    // One-time: threads 0..63 compute one token's Julia features each.
    if (t < TPB) {
        const int id = tok[base + t];
        const float2 c = reinterpret_cast<const float2*>(ctab)[id];
        float loc[NFEAT];
        float zr = 0.0f, zi = 0.0f;
#pragma unroll
        for (int st = 0; st < STEPS; ++st) {
            float nzr = zr * zr - zi * zi + c.x;
            float nzi = 2.0f * zr * zi + c.y;
            zr = nzr; zi = nzi;
            loc[2 * st]     = zr;
            loc[2 * st + 1] = zi;
        }
#pragma unroll
        for (int q = 0; q < 4; ++q)
            fs4[t * 4 + q] = reinterpret_cast<const float4*>(loc)[q];
    }

    // W packed across dim-pairs: wp[j][k] = { W[4t+2j][k], W[4t+2j+1][k] } * s
    floatx2 wp[2][NFEAT];
#pragma unroll
    for (int j = 0; j < 2; ++j) {
        const float4* r0 = reinterpret_cast<const float4*>(W + (size_t)(4 * t + 2 * j)     * NFEAT);
        const float4* r1 = reinterpret_cast<const float4*>(W + (size_t)(4 * t + 2 * j + 1) * NFEAT);
#pragma unroll
        for (int q = 0; q < 4; ++q) {
            float4 a = r0[q];
            float4 b = r1[q];
            wp[j][4 * q + 0] = floatx2{a.x * s, b.x * s};
            wp[j][4 * q + 1] = floatx2{a.y * s, b.y * s};
            wp[j][4 * q + 2] = floatx2{a.z * s, b.z * s};
            wp[j][4 * q + 3] = floatx2{a.w * s, b.w * s};
        }
    }

    __syncthreads();

// One float4 chunk (4 k-values) of one token into both packed accumulators.
#define ACC4(pa, pb, v, kb)                                                  \
    { floatx2 fbv;                                                           \
      fbv = floatx2{(v).x, (v).x}; pa += fbv * wp[0][(kb) + 0]; pb += fbv * wp[1][(kb) + 0]; \
      fbv = floatx2{(v).y, (v).y}; pa += fbv * wp[0][(kb) + 1]; pb += fbv * wp[1][(kb) + 1]; \
      fbv = floatx2{(v).z, (v).z}; pa += fbv * wp[0][(kb) + 2]; pb += fbv * wp[1][(kb) + 2]; \
      fbv = floatx2{(v).w, (v).w}; pa += fbv * wp[0][(kb) + 3]; pb += fbv * wp[1][(kb) + 3]; }

#define EMIT(p0, p1, row)                                                    \
    { float4 o; o.x = (p0).x; o.y = (p0).y; o.z = (p1).x; o.w = (p1).y;      \
      reinterpret_cast<float4*>(out + (size_t)(row) * EMBED)[t] = o; }

// Compute + store one PAIR of tokens from 8 float4 feat chunks.
#define PHASE(C0, C1, C2, C3, C4, C5, C6, C7, row)                           \
    { floatx2 q00 = {0.f, 0.f}, q01 = {0.f, 0.f};                            \
      floatx2 q10 = {0.f, 0.f}, q11 = {0.f, 0.f};                            \
      ACC4(q00, q01, C0, 0); ACC4(q00, q01, C1, 4);                          \
      ACC4(q00, q01, C2, 8); ACC4(q00, q01, C3, 12);                         \
      ACC4(q10, q11, C4, 0); ACC4(q10, q11, C5, 4);                          \
      ACC4(q10, q11, C6, 8); ACC4(q10, q11, C7, 12);                         \
      EMIT(q00, q01, (row)); EMIT(q10, q11, (row) + 1); }

    // Prologue: pair 0 into reg-set A.
    float4 A0 = fs4[0], A1 = fs4[1], A2 = fs4[2], A3 = fs4[3];
    float4 A4 = fs4[4], A5 = fs4[5], A6 = fs4[6], A7 = fs4[7];
    float4 B0, B1, B2, B3, B4, B5, B6, B7;

#pragma unroll 1
    for (int i = 0; i < TPB; i += 4) {
        const int n1 = (i + 2 < TPB) ? (i + 2) : i;   // next pair
        const int n2 = (i + 4 < TPB) ? (i + 4) : i;   // pair after next

        // Phase A: prefetch pair n1 -> B, compute/store pair i from A.
        B0 = fs4[n1 * 4 + 0]; B1 = fs4[n1 * 4 + 1];
        B2 = fs4[n1 * 4 + 2]; B3 = fs4[n1 * 4 + 3];
        B4 = fs4[n1 * 4 + 4]; B5 = fs4[n1 * 4 + 5];
        B6 = fs4[n1 * 4 + 6]; B7 = fs4[n1 * 4 + 7];
        PHASE(A0, A1, A2, A3, A4, A5, A6, A7, base + i);

        // Phase B: prefetch pair n2 -> A, compute/store pair n1 from B.
        A0 = fs4[n2 * 4 + 0]; A1 = fs4[n2 * 4 + 1];
        A2 = fs4[n2 * 4 + 2]; A3 = fs4[n2 * 4 + 3];
        A4 = fs4[n2 * 4 + 4]; A5 = fs4[n2 * 4 + 5];
        A6 = fs4[n2 * 4 + 6]; A7 = fs4[n2 * 4 + 7];
        PHASE(B0, B1, B2, B3, B4, B5, B6, B7, base + n1);
    }
}

extern "C" void kernel_launch(void* const* d_in, const int* in_sizes, int n_in,
                              void* d_out, int out_size, void* d_ws, size_t ws_size,
                              hipStream_t stream) {
    const int*   tok   = (const int*)d_in[0];
    const float* ctab  = (const float*)d_in[1];
    const float* W     = (const float*)d_in[2];
    const float* scale = (const float*)d_in[3];
    float*       out   = (float*)d_out;

    FractalEmbedding_30365418782757_kernel<<<GRID, BLOCK, 0, stream>>>(tok, ctab, W, scale, out);
}

// Round 7
// 52.080 us; speedup vs baseline: 1.4704x; 1.4704x over previous
//
#include <hip/hip_runtime.h>

// FractalEmbedding: out[b,l,d] = scale * sum_f feats(token)[f] * W[d,f]
// feats = 8-step Julia iteration on c_table[token], interleaved (zr,zi).
//
// B=8, L=8192 -> 65536 tokens; D=1024; 16 features. Output 268 MB f32.
// History: R5 (best, 50.3us) = 38us store-floor + ~12us unhidden stall at
// 4 waves/SIMD. R6 (register ping-pong) spilled past the 128-VGPR cap and
// regressed. This version buys OVERLAP with TLP instead of registers:
//  - 2 dims/thread, BLOCK=512, __launch_bounds__(512,8): wp = 32 VGPR,
//    total ~60 VGPR -> 8 waves/SIMD (2x R5). Viable only because Julia is
//    LDS-dedup'd (R3's 2-dim attempt paid 2x Julia recompute; now the only
//    duplication is cheap broadcast ds_reads).
//  - one token per iteration, NO register prefetch, #pragma unroll 1:
//    keep live set under the 64-VGPR cap (R6 lesson).
//  - unchanged: feats computed once per block by threads 0..63 into 4 KB
//    LDS (bit-identical), packed floatx2 dot (v_pk_fma_f32, per-dim chain
//    order = reference k ascending), plain stores, zero global loads in
//    the main loop, exact residency (GRID=1024 -> 4 blocks/CU, no tail).

#define STEPS 8
#define NFEAT (2 * STEPS)
#define EMBED 1024
#define NTOK (8 * 8192)
#define TPB 64                 // tokens per block
#define BLOCK 512
#define GRID (NTOK / TPB)      // 1024

typedef float floatx2 __attribute__((ext_vector_type(2)));

__global__ __launch_bounds__(BLOCK, 8) void FractalEmbedding_30365418782757_kernel(
    const int* __restrict__ tok,
    const float* __restrict__ ctab,   // (V, 2)
    const float* __restrict__ W,      // (1024, 16) row-major
    const float* __restrict__ scale_p,
    float* __restrict__ out)          // (NTOK, 1024)
{
    const int t = threadIdx.x;  // thread t -> output dims 2t, 2t+1
    const float s = *scale_p;

    __shared__ float4 fs4[TPB * 4];   // 4 KB: per-token features

    const int base = blockIdx.x * TPB;

    // One-time: threads 0..63 compute one token's Julia features each.
    if (t < TPB) {
        const int id = tok[base + t];
        const float2 c = reinterpret_cast<const float2*>(ctab)[id];
        float loc[NFEAT];
        float zr = 0.0f, zi = 0.0f;
#pragma unroll
        for (int st = 0; st < STEPS; ++st) {
            float nzr = zr * zr - zi * zi + c.x;
            float nzi = 2.0f * zr * zi + c.y;
            zr = nzr; zi = nzi;
            loc[2 * st]     = zr;
            loc[2 * st + 1] = zi;
        }
#pragma unroll
        for (int q = 0; q < 4; ++q)
            fs4[t * 4 + q] = reinterpret_cast<const float4*>(loc)[q];
    }

    // W packed across this thread's dim pair: wp[k] = { W[2t][k], W[2t+1][k] } * s
    floatx2 wp[NFEAT];
    {
        const float4* r0 = reinterpret_cast<const float4*>(W + (size_t)(2 * t)     * NFEAT);
        const float4* r1 = reinterpret_cast<const float4*>(W + (size_t)(2 * t + 1) * NFEAT);
#pragma unroll
        for (int q = 0; q < 4; ++q) {
            float4 a = r0[q];
            float4 b = r1[q];
            wp[4 * q + 0] = floatx2{a.x * s, b.x * s};
            wp[4 * q + 1] = floatx2{a.y * s, b.y * s};
            wp[4 * q + 2] = floatx2{a.z * s, b.z * s};
            wp[4 * q + 3] = floatx2{a.w * s, b.w * s};
        }
    }

    __syncthreads();

    float2* out2 = reinterpret_cast<float2*>(out);

    // Main loop: 4 broadcast ds_read_b128 + 16 v_pk_fma + 1 dwordx2 store
    // per token. No global loads, minimal live registers; 8 waves/SIMD
    // round-robin past the lgkm and store-WAR waits.
#pragma unroll 1
    for (int i = 0; i < TPB; ++i) {
        const float4 g0 = fs4[i * 4 + 0];
        const float4 g1 = fs4[i * 4 + 1];
        const float4 g2 = fs4[i * 4 + 2];
        const float4 g3 = fs4[i * 4 + 3];

        // Per-dim chain order is exactly k = 0..15 (reference order).
        floatx2 acc = {0.f, 0.f};
        acc += floatx2{g0.x, g0.x} * wp[0];
        acc += floatx2{g0.y, g0.y} * wp[1];
        acc += floatx2{g0.z, g0.z} * wp[2];
        acc += floatx2{g0.w, g0.w} * wp[3];
        acc += floatx2{g1.x, g1.x} * wp[4];
        acc += floatx2{g1.y, g1.y} * wp[5];
        acc += floatx2{g1.z, g1.z} * wp[6];
        acc += floatx2{g1.w, g1.w} * wp[7];
        acc += floatx2{g2.x, g2.x} * wp[8];
        acc += floatx2{g2.y, g2.y} * wp[9];
        acc += floatx2{g2.z, g2.z} * wp[10];
        acc += floatx2{g2.w, g2.w} * wp[11];
        acc += floatx2{g3.x, g3.x} * wp[12];
        acc += floatx2{g3.y, g3.y} * wp[13];
        acc += floatx2{g3.z, g3.z} * wp[14];
        acc += floatx2{g3.w, g3.w} * wp[15];

        float2 o; o.x = acc.x; o.y = acc.y;
        out2[(size_t)(base + i) * (EMBED / 2) + t] = o;
    }
}

extern "C" void kernel_launch(void* const* d_in, const int* in_sizes, int n_in,
                              void* d_out, int out_size, void* d_ws, size_t ws_size,
                              hipStream_t stream) {
    const int*   tok   = (const int*)d_in[0];
    const float* ctab  = (const float*)d_in[1];
    const float* W     = (const float*)d_in[2];
    const float* scale = (const float*)d_in[3];
    float*       out   = (float*)d_out;

    FractalEmbedding_30365418782757_kernel<<<GRID, BLOCK, 0, stream>>>(tok, ctab, W, scale, out);
}